// Round 1
// baseline (395.621 us; speedup 1.0000x reference)
//
#include <hip/hip_runtime.h>
#include <hip/hip_bf16.h>

typedef _Float16 half8 __attribute__((ext_vector_type(8)));
typedef _Float16 half4v __attribute__((ext_vector_type(4)));
typedef float floatx4 __attribute__((ext_vector_type(4)));

#define C_DIM 256
#define M_DIM 512
#define HW 4096
#define TAU 0.0025f

// ---------------- prep: memN = l2norm(relu(relu(mem@w1+b1)@w2+b2)) ----------------
// outputs: mNh/mNl = fp16 hi/lo split [512][256]; mNt = fp16 transposed [256][512]
__global__ __launch_bounds__(128) void prep_kernel(
    const float* __restrict__ memory, const float* __restrict__ w1,
    const float* __restrict__ b1, const float* __restrict__ w2,
    const float* __restrict__ b2,
    _Float16* __restrict__ mNh, _Float16* __restrict__ mNl,
    _Float16* __restrict__ mNt)
{
  __shared__ float sm[256];
  __shared__ float sh[128];
  __shared__ float s_part[2];
  __shared__ float s_tot;
  const int r = blockIdx.x;
  const int t = threadIdx.x;
  sm[t]       = memory[r * C_DIM + t];
  sm[t + 128] = memory[r * C_DIM + t + 128];
  __syncthreads();
  float acc = b1[t];
#pragma unroll 8
  for (int c = 0; c < 256; ++c) acc = fmaf(sm[c], w1[c * 128 + t], acc);
  sh[t] = fmaxf(acc, 0.f);
  __syncthreads();
  float o0 = b2[t], o1 = b2[t + 128];
#pragma unroll 8
  for (int k = 0; k < 128; ++k) {
    float h = sh[k];
    o0 = fmaf(h, w2[k * 256 + t], o0);
    o1 = fmaf(h, w2[k * 256 + t + 128], o1);
  }
  o0 = fmaxf(o0, 0.f);
  o1 = fmaxf(o1, 0.f);
  float ss = o0 * o0 + o1 * o1;
#pragma unroll
  for (int off = 32; off >= 1; off >>= 1) ss += __shfl_down(ss, off);
  if ((t & 63) == 0) s_part[t >> 6] = ss;
  __syncthreads();
  if (t == 0) s_tot = s_part[0] + s_part[1];
  __syncthreads();
  const float inv = 1.f / fmaxf(sqrtf(s_tot), 1e-12f);
  const float v0 = o0 * inv, v1 = o1 * inv;
  const _Float16 h0 = (_Float16)v0, h1 = (_Float16)v1;
  mNh[r * C_DIM + t]        = h0;
  mNh[r * C_DIM + t + 128]  = h1;
  mNl[r * C_DIM + t]        = (_Float16)(v0 - (float)h0);
  mNl[r * C_DIM + t + 128]  = (_Float16)(v1 - (float)h1);
  mNt[t * M_DIM + r]        = h0;
  mNt[(t + 128) * M_DIM + r] = h1;
}

// ---------------- fused main kernel: 64 pixels per block ----------------
__global__ __launch_bounds__(512, 2) void main_kernel(
    const float* __restrict__ x,
    const _Float16* __restrict__ mNh, const _Float16* __restrict__ mNl,
    const _Float16* __restrict__ mNt,
    float* __restrict__ out, float* __restrict__ attmap)
{
  __shared__ _Float16 Xh[64][264];    // x tile fp16 hi  (reused as out staging)
  __shared__ _Float16 Xl[64][264];    // x tile fp16 lo
  __shared__ _Float16 attb[64][520];  // att tile fp16
  __shared__ float s_red[64][8];
  __shared__ float s_stat[64];
  __shared__ float s_inv[64];
  __shared__ float s_sumsq[64];

  const int tid  = threadIdx.x;
  const int wave = tid >> 6;     // 0..7
  const int lane = tid & 63;
  const int q    = lane >> 4;    // quad within wave
  const int c16  = lane & 15;
  const int px   = tid & 63;     // pixel for staging phases
  const int g    = tid >> 6;

  const int blk = blockIdx.x;          // 1024 blocks
  const int img = blk >> 6;            // 64 blocks per image
  const int hw0 = (blk & 63) * 64;
  const float* __restrict__ xb = x + (size_t)img * C_DIM * HW + hw0;

  if (tid < 64) s_sumsq[tid] = 0.f;
  __syncthreads();

  // ---- Phase A: load x tile, accumulate sumsq, split fp16, transpose into LDS
  float part = 0.f;
#pragma unroll
  for (int i = 0; i < 8; ++i) {
    const int cb = i * 32 + g * 4;
    const float v0 = xb[(size_t)(cb + 0) * HW + px];
    const float v1 = xb[(size_t)(cb + 1) * HW + px];
    const float v2 = xb[(size_t)(cb + 2) * HW + px];
    const float v3 = xb[(size_t)(cb + 3) * HW + px];
    part += v0 * v0 + v1 * v1 + v2 * v2 + v3 * v3;
    const _Float16 h0 = (_Float16)v0, h1 = (_Float16)v1, h2 = (_Float16)v2, h3 = (_Float16)v3;
    half4v hv = {h0, h1, h2, h3};
    half4v lv = {(_Float16)(v0 - (float)h0), (_Float16)(v1 - (float)h1),
                 (_Float16)(v2 - (float)h2), (_Float16)(v3 - (float)h3)};
    *(half4v*)&Xh[px][cb] = hv;
    *(half4v*)&Xl[px][cb] = lv;
  }
  atomicAdd(&s_sumsq[px], part);
  __syncthreads();
  if (tid < 64) s_inv[tid] = 1.f / fmaxf(sqrtf(s_sumsq[tid]), 1e-12f);
  __syncthreads();

  // ---- Phase B: GEMM1  S[64][512] = Xsplit @ memN^T  (split-fp16, 3-term)
  floatx4 acc[4][4];
#pragma unroll
  for (int mt = 0; mt < 4; ++mt)
#pragma unroll
    for (int nt = 0; nt < 4; ++nt) {
      floatx4 z = {0.f, 0.f, 0.f, 0.f};
      acc[mt][nt] = z;
    }

#pragma unroll
  for (int kb = 0; kb < 8; ++kb) {
    const int k0 = kb * 32 + q * 8;
    half8 ah[4], al[4];
#pragma unroll
    for (int mt = 0; mt < 4; ++mt) {
      ah[mt] = *(const half8*)&Xh[mt * 16 + c16][k0];
      al[mt] = *(const half8*)&Xl[mt * 16 + c16][k0];
    }
#pragma unroll
    for (int nt = 0; nt < 4; ++nt) {
      const int n = wave * 64 + nt * 16 + c16;
      const half8 bh = *(const half8*)(mNh + (size_t)n * C_DIM + k0);
      const half8 bl = *(const half8*)(mNl + (size_t)n * C_DIM + k0);
#pragma unroll
      for (int mt = 0; mt < 4; ++mt) {
        acc[mt][nt] = __builtin_amdgcn_mfma_f32_16x16x32_f16(ah[mt], bh, acc[mt][nt], 0, 0, 0);
        acc[mt][nt] = __builtin_amdgcn_mfma_f32_16x16x32_f16(ah[mt], bl, acc[mt][nt], 0, 0, 0);
        acc[mt][nt] = __builtin_amdgcn_mfma_f32_16x16x32_f16(al[mt], bh, acc[mt][nt], 0, 0, 0);
      }
    }
  }

  // ---- Phase C: scale by 1/||x||, softmax, shrink, renorm (all fp32 in regs)
  // C/D layout: value (m = mt*16 + q*4 + r, n = wave*64 + nt*16 + c16)
#pragma unroll
  for (int mt = 0; mt < 4; ++mt)
#pragma unroll
    for (int r = 0; r < 4; ++r) {
      const float iv = s_inv[mt * 16 + q * 4 + r];
#pragma unroll
      for (int nt = 0; nt < 4; ++nt) acc[mt][nt][r] *= iv;
    }

  // row max
#pragma unroll
  for (int mt = 0; mt < 4; ++mt)
#pragma unroll
    for (int r = 0; r < 4; ++r) {
      float v = fmaxf(fmaxf(acc[mt][0][r], acc[mt][1][r]), fmaxf(acc[mt][2][r], acc[mt][3][r]));
      v = fmaxf(v, __shfl_xor(v, 1));
      v = fmaxf(v, __shfl_xor(v, 2));
      v = fmaxf(v, __shfl_xor(v, 4));
      v = fmaxf(v, __shfl_xor(v, 8));
      if (c16 == 0) s_red[mt * 16 + q * 4 + r][wave] = v;
    }
  __syncthreads();
  if (tid < 64) {
    float v = s_red[tid][0];
#pragma unroll
    for (int w = 1; w < 8; ++w) v = fmaxf(v, s_red[tid][w]);
    s_stat[tid] = v;
  }
  __syncthreads();

  // exp + row sum
#pragma unroll
  for (int mt = 0; mt < 4; ++mt)
#pragma unroll
    for (int r = 0; r < 4; ++r) {
      const float mx = s_stat[mt * 16 + q * 4 + r];
      float s = 0.f;
#pragma unroll
      for (int nt = 0; nt < 4; ++nt) {
        const float e = __expf(acc[mt][nt][r] - mx);
        acc[mt][nt][r] = e;
        s += e;
      }
      s += __shfl_xor(s, 1);
      s += __shfl_xor(s, 2);
      s += __shfl_xor(s, 4);
      s += __shfl_xor(s, 8);
      if (c16 == 0) s_red[mt * 16 + q * 4 + r][wave] = s;
    }
  __syncthreads();
  if (tid < 64) {
    float v = 0.f;
#pragma unroll
    for (int w = 0; w < 8; ++w) v += s_red[tid][w];
    s_stat[tid] = 1.f / v;  // sumExp >= 1 always
  }
  __syncthreads();

  // p = e/sum; t = relu(p - tau); row sum of t
#pragma unroll
  for (int mt = 0; mt < 4; ++mt)
#pragma unroll
    for (int r = 0; r < 4; ++r) {
      const float isum = s_stat[mt * 16 + q * 4 + r];
      float s = 0.f;
#pragma unroll
      for (int nt = 0; nt < 4; ++nt) {
        const float tv = fmaxf(acc[mt][nt][r] * isum - TAU, 0.f);
        acc[mt][nt][r] = tv;
        s += tv;
      }
      s += __shfl_xor(s, 1);
      s += __shfl_xor(s, 2);
      s += __shfl_xor(s, 4);
      s += __shfl_xor(s, 8);
      if (c16 == 0) s_red[mt * 16 + q * 4 + r][wave] = s;
    }
  __syncthreads();
  if (tid < 64) {
    float v = 0.f;
#pragma unroll
    for (int w = 0; w < 8; ++w) v += s_red[tid][w];
    s_stat[tid] = 1.f / fmaxf(v, 1e-12f);
  }
  __syncthreads();

  // att = t / sumT  -> attb (fp16)
#pragma unroll
  for (int mt = 0; mt < 4; ++mt)
#pragma unroll
    for (int r = 0; r < 4; ++r) {
      const int m = mt * 16 + q * 4 + r;
      const float rs = s_stat[m];
#pragma unroll
      for (int nt = 0; nt < 4; ++nt)
        attb[m][wave * 64 + nt * 16 + c16] = (_Float16)(acc[mt][nt][r] * rs);
    }
  __syncthreads();

  // ---- Phase D: write att_map (coalesced, 64 contiguous px per slot)
#pragma unroll
  for (int i = 0; i < 16; ++i) {
    const int n0 = (g + 8 * i) * 4;
    const half4v v = *(const half4v*)&attb[px][n0];
    float* dst = attmap + ((size_t)img * M_DIM + n0) * HW + hw0 + px;
    dst[0]            = (float)v[0];
    dst[(size_t)HW]   = (float)v[1];
    dst[(size_t)2*HW] = (float)v[2];
    dst[(size_t)3*HW] = (float)v[3];
  }

  // ---- Phase E: GEMM2  out[64][256] = att @ memN  (fp16)
  floatx4 acc2[4][2];
#pragma unroll
  for (int mt = 0; mt < 4; ++mt)
#pragma unroll
    for (int ct = 0; ct < 2; ++ct) {
      floatx4 z = {0.f, 0.f, 0.f, 0.f};
      acc2[mt][ct] = z;
    }
#pragma unroll
  for (int kb = 0; kb < 16; ++kb) {
    const int k0 = kb * 32 + q * 8;
    half8 a[4];
#pragma unroll
    for (int mt = 0; mt < 4; ++mt) a[mt] = *(const half8*)&attb[mt * 16 + c16][k0];
#pragma unroll
    for (int ct = 0; ct < 2; ++ct) {
      const int cc = wave * 32 + ct * 16 + c16;
      const half8 b = *(const half8*)(mNt + (size_t)cc * M_DIM + k0);
#pragma unroll
      for (int mt = 0; mt < 4; ++mt)
        acc2[mt][ct] = __builtin_amdgcn_mfma_f32_16x16x32_f16(a[mt], b, acc2[mt][ct], 0, 0, 0);
    }
  }

  // ---- Phase F/G: stage out tile through LDS (reuse Xh), coalesced store
#pragma unroll
  for (int mt = 0; mt < 4; ++mt)
#pragma unroll
    for (int ct = 0; ct < 2; ++ct)
#pragma unroll
      for (int r = 0; r < 4; ++r)
        Xh[mt * 16 + q * 4 + r][wave * 32 + ct * 16 + c16] = (_Float16)acc2[mt][ct][r];
  __syncthreads();
#pragma unroll
  for (int i = 0; i < 8; ++i) {
    const int c0 = (g + 8 * i) * 4;
    const half4v v = *(const half4v*)&Xh[px][c0];
    float* dst = out + ((size_t)img * C_DIM + c0) * HW + hw0 + px;
    dst[0]            = (float)v[0];
    dst[(size_t)HW]   = (float)v[1];
    dst[(size_t)2*HW] = (float)v[2];
    dst[(size_t)3*HW] = (float)v[3];
  }
}

extern "C" void kernel_launch(void* const* d_in, const int* in_sizes, int n_in,
                              void* d_out, int out_size, void* d_ws, size_t ws_size,
                              hipStream_t stream) {
  (void)in_sizes; (void)n_in; (void)out_size; (void)ws_size;
  const float* x      = (const float*)d_in[0];
  const float* memory = (const float*)d_in[1];
  const float* w1     = (const float*)d_in[2];
  const float* b1     = (const float*)d_in[3];
  const float* w2     = (const float*)d_in[4];
  const float* b2     = (const float*)d_in[5];
  float* out    = (float*)d_out;
  float* attmap = out + (size_t)16 * C_DIM * HW;  // output first, att_map second

  _Float16* mNh = (_Float16*)d_ws;
  _Float16* mNl = mNh + (size_t)M_DIM * C_DIM;
  _Float16* mNt = mNl + (size_t)M_DIM * C_DIM;

  hipLaunchKernelGGL(prep_kernel, dim3(M_DIM), dim3(128), 0, stream,
                     memory, w1, b1, w2, b2, mNh, mNl, mNt);
  hipLaunchKernelGGL(main_kernel, dim3(1024), dim3(512), 0, stream,
                     x, mNh, mNl, mNt, out, attmap);
}